// Round 1
// baseline (1170.728 us; speedup 1.0000x reference)
//
#include <hip/hip_runtime.h>

typedef __attribute__((ext_vector_type(8))) short bf16x8;   // 8 bf16 = 4 VGPRs (MFMA A/B frag)
typedef __attribute__((ext_vector_type(4))) float f32x4;    // MFMA C/D frag
typedef __attribute__((ext_vector_type(4))) float f4;
typedef __attribute__((ext_vector_type(2))) unsigned int u32x2;
typedef __attribute__((ext_vector_type(4))) unsigned int u32x4;

#define HW   16384   // 128*128
#define FDIM 512

// pack bf16(trunc) of a (low 16) and b (high 16) in one v_perm_b32
__device__ __forceinline__ unsigned pkhi(float a, float b) {
    return __builtin_amdgcn_perm(__builtin_bit_cast(unsigned int, b),
                                 __builtin_bit_cast(unsigned int, a),
                                 0x07060302u);
}
__device__ __forceinline__ float trhi(float a) {
    return __builtin_bit_cast(float, __builtin_bit_cast(unsigned int, a) & 0xFFFF0000u);
}
__device__ __forceinline__ unsigned pklo(float a, float b) {
    return pkhi(a - trhi(a), b - trhi(b));
}

// ---------------------------------------------------------------------------
// Prologue: convert W[e,c,f] fp32 -> bf16 hi/lo in d_ws, n-reordered (n=c*16+e)
// and laid out in MFMA B-frag order: W'[kchunk 0..63][n 0..1023][8 bf16].
__global__ __launch_bounds__(256) void conv_w(const float* __restrict__ wts,
                                              unsigned short* __restrict__ wh,
                                              unsigned short* __restrict__ wl) {
    const int tid = blockIdx.x * 256 + threadIdx.x;   // 65536 threads
    const int n  = tid & 1023;
    const int kc = tid >> 10;                         // k-chunk 0..63
    const float* src = wts + (size_t)((n & 15) * 64 + (n >> 4)) * FDIM + kc * 8;
    f4 a = *(const f4*)src, b = *(const f4*)(src + 4);
    u32x4 h = { pkhi(a[0], a[1]), pkhi(a[2], a[3]), pkhi(b[0], b[1]), pkhi(b[2], b[3]) };
    u32x4 l = { pklo(a[0], a[1]), pklo(a[2], a[3]), pklo(b[0], b[1]), pklo(b[2], b[3]) };
    size_t off = ((size_t)kc * 1024 + n) * 8;
    *(u32x4*)(wh + off) = h;    // 16 B per thread, consecutive n -> coalesced
    *(u32x4*)(wl + off) = l;
}

// ---------------------------------------------------------------------------
// Main: C[m=pixel, n=c*16+e] = feat[m,:] . W[n,:]
// epilogue: out[b,c,h,w] = exp(-3.125 * sum_e (C - cent)^2)
// Changes vs prev round:
//   (1) XCD-aware block swizzle: each XCD owns a contiguous mb range; the 8
//       nb-siblings of an mb are dispatch-adjacent on the same XCD -> the
//       256 KB A-panel is fetched once per XCD L2 instead of 8x from HBM.
//   (2) Double-buffered A staging in LDS -> ONE barrier per K-step; the
//       fp32->bf16 pack + LDS write moved AFTER the MFMA cluster so pack VALU
//       and the av global-load latency hide under the 48 MFMAs (ILP).
//   (3) s_setprio(1) around the MFMA cluster (independent blocks per CU ->
//       the non-lockstep regime where setprio measured positive).
__global__ __launch_bounds__(256, 4) void duq_main(
    const float* __restrict__ feat,          // [8,512,128,128]
    const unsigned short* __restrict__ wh,   // [64][1024][8] bf16 hi
    const unsigned short* __restrict__ wl,   // [64][1024][8] bf16 lo
    const float* __restrict__ m_in,          // [16,64]
    const float* __restrict__ n_in,          // [64]
    float* __restrict__ out)                 // [8,64,128,128]
{
    __shared__ __align__(16) unsigned short Ah[2][128 * 40];  // dbuf, stride 40
    __shared__ __align__(16) unsigned short Al[2][128 * 40];  // total 40 KiB

    const int t  = threadIdx.x;
    const int bx = blockIdx.x;
    // XCD swizzle: raw blockIdx round-robins over 8 XCDs -> (bx&7) = XCD id.
    // mb = xcd*128 + (kb>>3): contiguous mb range per XCD; nb = kb&7 keeps
    // the 8 N-siblings of one mb adjacent in per-XCD dispatch order.
    const int kb = bx >> 3;
    const int nb = kb & 7;                    // N block: 1024/128
    const int mb = (bx & 7) * 128 + (kb >> 3);
    const int bidx = mb >> 7;
    const int hw0  = (mb & 127) << 7;

    // A staging: thread covers 4(f) x 4(p)
    const int fb = t & 7;
    const int pb = t >> 3;
    const float* ap = feat + (size_t)bidx * (FDIM * HW) + (size_t)(fb * 4) * HW + (hw0 + pb * 4);
    const int aw = (pb * 4) * 40 + fb * 4;

    const int lane = t & 63;
    const int wv = t >> 6;
    const int wm = wv >> 1, wn = wv & 1;      // 2x2 waves, 64x64 each
    const int l16 = lane & 15, qd = lane >> 4;
    const int ar = (wm * 64 + l16) * 40 + qd * 8;

    // B frag base for this lane: frag (kt,j) is 16 B at bgh + kt*32768 + j*128
    const size_t bgoff = ((size_t)qd * 1024 + (size_t)(nb * 128 + wn * 64 + l16)) * 8;
    const unsigned short* bgh = wh + bgoff;
    const unsigned short* bgl = wl + bgoff;

    f32x4 acc[4][4] = {};

    f4 av[4];
    #pragma unroll
    for (int i = 0; i < 4; ++i) av[i] = *(const f4*)(ap + (size_t)i * HW);

    // stage kt=0 into buffer 0
    #pragma unroll
    for (int j = 0; j < 4; ++j) {
        float a0 = av[0][j], a1 = av[1][j], a2 = av[2][j], a3 = av[3][j];
        u32x2 h, l;
        h[0] = pkhi(a0, a1); h[1] = pkhi(a2, a3);
        l[0] = pklo(a0, a1); l[1] = pklo(a2, a3);
        *(u32x2*)(&Ah[0][aw + j * 40]) = h;
        *(u32x2*)(&Al[0][aw + j * 40]) = l;
    }

    // preload B-frag (kt=0, j=0)
    bf16x8 cbh = *(const bf16x8*)(bgh);
    bf16x8 cbl = *(const bf16x8*)(bgl);
    size_t boff = 0;

    __syncthreads();

    for (int kt = 0; kt < 16; ++kt) {
        const int cur = kt & 1;

        // issue next A K-tile global loads early; vmcnt drains at the stage
        // (post-MFMA), so the ~HBM/L2 latency hides under the MFMA cluster
        if (kt < 15) {
            ap += 32 * HW;
            #pragma unroll
            for (int i = 0; i < 4; ++i) av[i] = *(const f4*)(ap + (size_t)i * HW);
        }

        // ---- A fragments from LDS buf[cur]
        bf16x8 fah[4], fal[4];
        #pragma unroll
        for (int i = 0; i < 4; ++i) {
            fah[i] = *(const bf16x8*)(&Ah[cur][ar + i * 640]);   // +16 rows * 40
            fal[i] = *(const bf16x8*)(&Al[cur][ar + i * 640]);
        }

        // ---- j-pipelined MFMA: load B-frag (j+1) from L2, compute j
        __builtin_amdgcn_s_setprio(1);
        #pragma unroll
        for (int j = 0; j < 4; ++j) {
            size_t bnext = boff + ((j == 3) ? (size_t)(32768 - 384) : (size_t)128);
            bf16x8 nbh = *(const bf16x8*)(bgh + bnext);   // final (kt=15,j=3) load is
            bf16x8 nbl = *(const bf16x8*)(bgl + bnext);   // discarded (ws slack covers OOB)
            #pragma unroll
            for (int i = 0; i < 4; ++i) {
                acc[i][j] = __builtin_amdgcn_mfma_f32_16x16x32_bf16(fah[i], cbh, acc[i][j], 0, 0, 0);
                acc[i][j] = __builtin_amdgcn_mfma_f32_16x16x32_bf16(fah[i], cbl, acc[i][j], 0, 0, 0);
                acc[i][j] = __builtin_amdgcn_mfma_f32_16x16x32_bf16(fal[i], cbh, acc[i][j], 0, 0, 0);
            }
            cbh = nbh; cbl = nbl; boff = bnext;
        }
        __builtin_amdgcn_s_setprio(0);

        // ---- stage next K-tile into buf[cur^1]; single barrier per kt.
        // Safe: in the window (barrier kt-1, barrier kt) all waves read
        // buf[cur] and write buf[cur^1] only.
        if (kt < 15) {
            const int nxtb = cur ^ 1;
            #pragma unroll
            for (int j = 0; j < 4; ++j) {
                float a0 = av[0][j], a1 = av[1][j], a2 = av[2][j], a3 = av[3][j];
                u32x2 h, l;
                h[0] = pkhi(a0, a1); h[1] = pkhi(a2, a3);
                l[0] = pklo(a0, a1); l[1] = pklo(a2, a3);
                *(u32x2*)(&Ah[nxtb][aw + j * 40]) = h;
                *(u32x2*)(&Al[nxtb][aw + j * 40]) = l;
            }
            __syncthreads();
        }
    }

    // ---- epilogue: subtract centroid, square, e-reduce (16 lanes), exp, store
    float centv[4];
    #pragma unroll
    for (int j = 0; j < 4; ++j) {
        int cj = nb * 8 + wn * 4 + j;
        centv[j] = m_in[l16 * 64 + cj] / n_in[cj];
    }
    #pragma unroll
    for (int i = 0; i < 4; ++i) {
        #pragma unroll
        for (int j = 0; j < 4; ++j) {
            float s0 = acc[i][j][0] - centv[j]; s0 *= s0;
            float s1 = acc[i][j][1] - centv[j]; s1 *= s1;
            float s2 = acc[i][j][2] - centv[j]; s2 *= s2;
            float s3 = acc[i][j][3] - centv[j]; s3 *= s3;
            #pragma unroll
            for (int msk = 1; msk < 16; msk <<= 1) {
                s0 += __shfl_xor(s0, msk, 64);
                s1 += __shfl_xor(s1, msk, 64);
                s2 += __shfl_xor(s2, msk, 64);
                s3 += __shfl_xor(s3, msk, 64);
            }
            if (l16 == 0) {
                int cj = nb * 8 + wn * 4 + j;
                f4 o;
                o[0] = __expf(s0 * -3.125f);
                o[1] = __expf(s1 * -3.125f);
                o[2] = __expf(s2 * -3.125f);
                o[3] = __expf(s3 * -3.125f);
                size_t off = ((size_t)(bidx * 64 + cj)) * HW
                           + (size_t)(hw0 + wm * 64 + i * 16 + qd * 4);
                *(f4*)(out + off) = o;
            }
        }
    }
}

// ---------------------------------------------------------------------------
// Fallback (R2 kernel, LDS-staged B) if ws is too small for W' precompute.
__global__ __launch_bounds__(256) void duq_fallback(
    const float* __restrict__ feat, const float* __restrict__ wts,
    const float* __restrict__ m_in, const float* __restrict__ n_in,
    float* __restrict__ out)
{
    __shared__ __align__(16) unsigned short Ah[128 * 40];
    __shared__ __align__(16) unsigned short Al[128 * 40];
    __shared__ __align__(16) unsigned short Bh[128 * 40];
    __shared__ __align__(16) unsigned short Bl[128 * 40];

    const int t  = threadIdx.x;
    const int bx = blockIdx.x;
    const int nb = bx & 7;
    const int mb = bx >> 3;
    const int bidx = mb >> 7;
    const int hw0  = (mb & 127) << 7;

    const int fb = t & 7;
    const int pb = t >> 3;
    const float* ap = feat + (size_t)bidx * (FDIM * HW) + (size_t)(fb * 4) * HW + (hw0 + pb * 4);

    const int bn  = t >> 1;
    const int bh_ = t & 1;
    const int ng  = nb * 128 + bn;
    const float* bp = wts + (size_t)((ng & 15) * 64 + (ng >> 4)) * FDIM + bh_ * 16;

    unsigned short* awH = &Ah[(pb * 4) * 40 + fb * 4];
    unsigned short* awL = &Al[(pb * 4) * 40 + fb * 4];
    unsigned short* bwH = &Bh[bn * 40 + bh_ * 16];
    unsigned short* bwL = &Bl[bn * 40 + bh_ * 16];

    const int lane = t & 63;
    const int wv = t >> 6;
    const int wm = wv >> 1, wn = wv & 1;
    const int l16 = lane & 15, qd = lane >> 4;

    const unsigned short* arH = &Ah[(wm * 64 + l16) * 40 + qd * 8];
    const unsigned short* arL = &Al[(wm * 64 + l16) * 40 + qd * 8];
    const unsigned short* brH = &Bh[(wn * 64 + l16) * 40 + qd * 8];
    const unsigned short* brL = &Bl[(wn * 64 + l16) * 40 + qd * 8];

    f32x4 acc[4][4] = {};

    f4 av[4], bv[4];
    #pragma unroll
    for (int i = 0; i < 4; ++i) av[i] = *(const f4*)(ap + (size_t)i * HW);
    #pragma unroll
    for (int q = 0; q < 4; ++q) bv[q] = *(const f4*)(bp + q * 4);

    for (int kt = 0; kt < 16; ++kt) {
        __syncthreads();
        #pragma unroll
        for (int j = 0; j < 4; ++j) {
            float a0 = av[0][j], a1 = av[1][j], a2 = av[2][j], a3 = av[3][j];
            u32x2 h, l;
            h[0] = pkhi(a0, a1); h[1] = pkhi(a2, a3);
            l[0] = pklo(a0, a1); l[1] = pklo(a2, a3);
            *(u32x2*)(awH + j * 40) = h;
            *(u32x2*)(awL + j * 40) = l;
        }
        {
            u32x4 h0 = { pkhi(bv[0][0], bv[0][1]), pkhi(bv[0][2], bv[0][3]),
                         pkhi(bv[1][0], bv[1][1]), pkhi(bv[1][2], bv[1][3]) };
            u32x4 h1 = { pkhi(bv[2][0], bv[2][1]), pkhi(bv[2][2], bv[2][3]),
                         pkhi(bv[3][0], bv[3][1]), pkhi(bv[3][2], bv[3][3]) };
            u32x4 l0 = { pklo(bv[0][0], bv[0][1]), pklo(bv[0][2], bv[0][3]),
                         pklo(bv[1][0], bv[1][1]), pklo(bv[1][2], bv[1][3]) };
            u32x4 l1 = { pklo(bv[2][0], bv[2][1]), pklo(bv[2][2], bv[2][3]),
                         pklo(bv[3][0], bv[3][1]), pklo(bv[3][2], bv[3][3]) };
            *(u32x4*)(bwH)     = h0;  *(u32x4*)(bwH + 8) = h1;
            *(u32x4*)(bwL)     = l0;  *(u32x4*)(bwL + 8) = l1;
        }
        __syncthreads();

        if (kt < 15) {
            ap += 32 * HW;
            bp += 32;
            #pragma unroll
            for (int i = 0; i < 4; ++i) av[i] = *(const f4*)(ap + (size_t)i * HW);
            #pragma unroll
            for (int q = 0; q < 4; ++q) bv[q] = *(const f4*)(bp + q * 4);
        }

        bf16x8 fah[4], fal[4];
        #pragma unroll
        for (int i = 0; i < 4; ++i) {
            fah[i] = *(const bf16x8*)(arH + i * 640);
            fal[i] = *(const bf16x8*)(arL + i * 640);
        }
        #pragma unroll
        for (int j = 0; j < 4; ++j) {
            bf16x8 fbh = *(const bf16x8*)(brH + j * 640);
            bf16x8 fbl = *(const bf16x8*)(brL + j * 640);
            #pragma unroll
            for (int i = 0; i < 4; ++i) {
                acc[i][j] = __builtin_amdgcn_mfma_f32_16x16x32_bf16(fah[i], fbh, acc[i][j], 0, 0, 0);
                acc[i][j] = __builtin_amdgcn_mfma_f32_16x16x32_bf16(fah[i], fbl, acc[i][j], 0, 0, 0);
                acc[i][j] = __builtin_amdgcn_mfma_f32_16x16x32_bf16(fal[i], fbh, acc[i][j], 0, 0, 0);
            }
        }
    }

    float centv[4];
    #pragma unroll
    for (int j = 0; j < 4; ++j) {
        int cj = nb * 8 + wn * 4 + j;
        centv[j] = m_in[l16 * 64 + cj] / n_in[cj];
    }
    #pragma unroll
    for (int i = 0; i < 4; ++i) {
        #pragma unroll
        for (int j = 0; j < 4; ++j) {
            float s0 = acc[i][j][0] - centv[j]; s0 *= s0;
            float s1 = acc[i][j][1] - centv[j]; s1 *= s1;
            float s2 = acc[i][j][2] - centv[j]; s2 *= s2;
            float s3 = acc[i][j][3] - centv[j]; s3 *= s3;
            #pragma unroll
            for (int msk = 1; msk < 16; msk <<= 1) {
                s0 += __shfl_xor(s0, msk, 64);
                s1 += __shfl_xor(s1, msk, 64);
                s2 += __shfl_xor(s2, msk, 64);
                s3 += __shfl_xor(s3, msk, 64);
            }
            if (l16 == 0) {
                int cj = nb * 8 + wn * 4 + j;
                f4 o;
                o[0] = __expf(s0 * -3.125f);
                o[1] = __expf(s1 * -3.125f);
                o[2] = __expf(s2 * -3.125f);
                o[3] = __expf(s3 * -3.125f);
                size_t off = ((size_t)(bidx * 64 + cj)) * HW
                           + (size_t)(hw0 + wm * 64 + i * 16 + qd * 4);
                *(f4*)(out + off) = o;
            }
        }
    }
}

extern "C" void kernel_launch(void* const* d_in, const int* in_sizes, int n_in,
                              void* d_out, int out_size, void* d_ws, size_t ws_size,
                              hipStream_t stream) {
    const float* feat = (const float*)d_in[0];
    const float* wts  = (const float*)d_in[1];
    const float* mbuf = (const float*)d_in[2];
    const float* nbuf = (const float*)d_in[3];
    float* out = (float*)d_out;

    // W' needs 2 MB + 128 KB slack (discarded tail prefetch reads past wl end)
    if (ws_size >= (size_t)(2 * 1024 * 1024 + 128 * 1024)) {
        unsigned short* wh = (unsigned short*)d_ws;
        unsigned short* wl = wh + 512 * 1024;   // 1 MB in
        conv_w<<<dim3(256), dim3(256), 0, stream>>>(wts, wh, wl);
        duq_main<<<dim3(1024 * 8), dim3(256), 0, stream>>>(feat, wh, wl, mbuf, nbuf, out);
    } else {
        duq_fallback<<<dim3(1024 * 8), dim3(256), 0, stream>>>(feat, wts, mbuf, nbuf, out);
    }
}

// Round 2
// 707.812 us; speedup vs baseline: 1.6540x; 1.6540x over previous
//
#include <hip/hip_runtime.h>

typedef __attribute__((ext_vector_type(8))) short bf16x8;   // 8 bf16 = 4 VGPRs (MFMA A/B frag)
typedef __attribute__((ext_vector_type(4))) float f32x4;    // MFMA C/D frag
typedef __attribute__((ext_vector_type(4))) float f4;
typedef __attribute__((ext_vector_type(2))) unsigned int u32x2;
typedef __attribute__((ext_vector_type(4))) unsigned int u32x4;

#define HW   16384   // 128*128
#define FDIM 512

// pack bf16(trunc) of a (low 16) and b (high 16) in one v_perm_b32
__device__ __forceinline__ unsigned pkhi(float a, float b) {
    return __builtin_amdgcn_perm(__builtin_bit_cast(unsigned int, b),
                                 __builtin_bit_cast(unsigned int, a),
                                 0x07060302u);
}
__device__ __forceinline__ float trhi(float a) {
    return __builtin_bit_cast(float, __builtin_bit_cast(unsigned int, a) & 0xFFFF0000u);
}
__device__ __forceinline__ unsigned pklo(float a, float b) {
    return pkhi(a - trhi(a), b - trhi(b));
}

// ---------------------------------------------------------------------------
// Prologue: convert W[e,c,f] fp32 -> bf16 hi/lo in d_ws, n-reordered (n=c*16+e)
// and laid out in MFMA B-frag order: W'[kchunk 0..63][n 0..1023][8 bf16].
__global__ __launch_bounds__(256) void conv_w(const float* __restrict__ wts,
                                              unsigned short* __restrict__ wh,
                                              unsigned short* __restrict__ wl) {
    const int tid = blockIdx.x * 256 + threadIdx.x;   // 65536 threads
    const int n  = tid & 1023;
    const int kc = tid >> 10;                         // k-chunk 0..63
    const float* src = wts + (size_t)((n & 15) * 64 + (n >> 4)) * FDIM + kc * 8;
    f4 a = *(const f4*)src, b = *(const f4*)(src + 4);
    u32x4 h = { pkhi(a[0], a[1]), pkhi(a[2], a[3]), pkhi(b[0], b[1]), pkhi(b[2], b[3]) };
    u32x4 l = { pklo(a[0], a[1]), pklo(a[2], a[3]), pklo(b[0], b[1]), pklo(b[2], b[3]) };
    size_t off = ((size_t)kc * 1024 + n) * 8;
    *(u32x4*)(wh + off) = h;    // 16 B per thread, consecutive n -> coalesced
    *(u32x4*)(wl + off) = l;
}

// ---------------------------------------------------------------------------
// Main: C[m=pixel, n=c*16+e] = feat[m,:] . W[n,:]
// epilogue: out[b,c,h,w] = exp(-3.125 * sum_e (C - cent)^2)
//
// R2: EXACT round-0 loop body (single LDS buffer, stage-at-top, 2 barriers --
// the shape the register allocator colors without spilling; R1's dbuf +
// post-MFMA stage spilled to scratch: WRITE_SIZE 49 MB -> 1.59 GB) plus the
// ONE proven change from R1: XCD-aware block swizzle (FETCH 1.07 GB -> 0.44 GB).
__global__ __launch_bounds__(256, 4) void duq_main(
    const float* __restrict__ feat,          // [8,512,128,128]
    const unsigned short* __restrict__ wh,   // [64][1024][8] bf16 hi
    const unsigned short* __restrict__ wl,   // [64][1024][8] bf16 lo
    const float* __restrict__ m_in,          // [16,64]
    const float* __restrict__ n_in,          // [64]
    float* __restrict__ out)                 // [8,64,128,128]
{
    __shared__ __align__(16) unsigned short Ah[128 * 40];  // stride 40: 16B-aligned rows
    __shared__ __align__(16) unsigned short Al[128 * 40];

    const int t  = threadIdx.x;
    const int bx = blockIdx.x;
    // XCD swizzle: raw blockIdx round-robins over 8 XCDs -> (bx&7) = XCD id.
    // mb = xcd*128 + (kb>>3): contiguous mb range per XCD; nb = kb&7 keeps the
    // 8 N-siblings of one mb dispatch-adjacent on the same XCD -> each 256 KB
    // A-panel is fetched into that XCD's L2 once instead of 8x from HBM/L3.
    const int kb = bx >> 3;
    const int nb = kb & 7;                    // N block: 1024/128
    const int mb = (bx & 7) * 128 + (kb >> 3);
    const int bidx = mb >> 7;
    const int hw0  = (mb & 127) << 7;

    // A staging: thread covers 4(f) x 4(p)
    const int fb = t & 7;
    const int pb = t >> 3;
    const float* ap = feat + (size_t)bidx * (FDIM * HW) + (size_t)(fb * 4) * HW + (hw0 + pb * 4);
    unsigned short* awH = &Ah[(pb * 4) * 40 + fb * 4];
    unsigned short* awL = &Al[(pb * 4) * 40 + fb * 4];

    const int lane = t & 63;
    const int wv = t >> 6;
    const int wm = wv >> 1, wn = wv & 1;      // 2x2 waves, 64x64 each
    const int l16 = lane & 15, qd = lane >> 4;

    const unsigned short* arH = &Ah[(wm * 64 + l16) * 40 + qd * 8];
    const unsigned short* arL = &Al[(wm * 64 + l16) * 40 + qd * 8];

    // B frag base for this lane: frag (kt,j) is 16 B at bgh + kt*32768 + j*128
    const size_t bgoff = ((size_t)qd * 1024 + (size_t)(nb * 128 + wn * 64 + l16)) * 8;
    const unsigned short* bgh = wh + bgoff;
    const unsigned short* bgl = wl + bgoff;

    f32x4 acc[4][4] = {};

    f4 av[4];
    #pragma unroll
    for (int i = 0; i < 4; ++i) av[i] = *(const f4*)(ap + (size_t)i * HW);

    // preload B-frag (kt=0, j=0)
    bf16x8 cbh = *(const bf16x8*)(bgh);
    bf16x8 cbl = *(const bf16x8*)(bgl);
    size_t boff = 0;

    for (int kt = 0; kt < 16; ++kt) {
        __syncthreads();
        // ---- stage A (4x4 reg transpose, hi/lo split)
        #pragma unroll
        for (int j = 0; j < 4; ++j) {
            float a0 = av[0][j], a1 = av[1][j], a2 = av[2][j], a3 = av[3][j];
            u32x2 h, l;
            h[0] = pkhi(a0, a1); h[1] = pkhi(a2, a3);
            l[0] = pklo(a0, a1); l[1] = pklo(a2, a3);
            *(u32x2*)(awH + j * 40) = h;
            *(u32x2*)(awL + j * 40) = l;
        }
        __syncthreads();

        // ---- prefetch next A K-tile (overlaps MFMA phase)
        if (kt < 15) {
            ap += 32 * HW;
            #pragma unroll
            for (int i = 0; i < 4; ++i) av[i] = *(const f4*)(ap + (size_t)i * HW);
        }

        // ---- A fragments from LDS
        bf16x8 fah[4], fal[4];
        #pragma unroll
        for (int i = 0; i < 4; ++i) {
            fah[i] = *(const bf16x8*)(arH + i * 640);   // +16 rows * 40
            fal[i] = *(const bf16x8*)(arL + i * 640);
        }

        // ---- j-pipelined MFMA: load B-frag (j+1) from L2, compute j
        #pragma unroll
        for (int j = 0; j < 4; ++j) {
            size_t bnext = boff + ((j == 3) ? (size_t)(32768 - 384) : (size_t)128);
            bf16x8 nbh = *(const bf16x8*)(bgh + bnext);   // final (kt=15,j=3) load is
            bf16x8 nbl = *(const bf16x8*)(bgl + bnext);   // discarded (ws slack covers OOB)
            #pragma unroll
            for (int i = 0; i < 4; ++i) {
                acc[i][j] = __builtin_amdgcn_mfma_f32_16x16x32_bf16(fah[i], cbh, acc[i][j], 0, 0, 0);
                acc[i][j] = __builtin_amdgcn_mfma_f32_16x16x32_bf16(fah[i], cbl, acc[i][j], 0, 0, 0);
                acc[i][j] = __builtin_amdgcn_mfma_f32_16x16x32_bf16(fal[i], cbh, acc[i][j], 0, 0, 0);
            }
            cbh = nbh; cbl = nbl; boff = bnext;
        }
    }

    // ---- epilogue: subtract centroid, square, e-reduce (16 lanes), exp, store
    float centv[4];
    #pragma unroll
    for (int j = 0; j < 4; ++j) {
        int cj = nb * 8 + wn * 4 + j;
        centv[j] = m_in[l16 * 64 + cj] / n_in[cj];
    }
    #pragma unroll
    for (int i = 0; i < 4; ++i) {
        #pragma unroll
        for (int j = 0; j < 4; ++j) {
            float s0 = acc[i][j][0] - centv[j]; s0 *= s0;
            float s1 = acc[i][j][1] - centv[j]; s1 *= s1;
            float s2 = acc[i][j][2] - centv[j]; s2 *= s2;
            float s3 = acc[i][j][3] - centv[j]; s3 *= s3;
            #pragma unroll
            for (int msk = 1; msk < 16; msk <<= 1) {
                s0 += __shfl_xor(s0, msk, 64);
                s1 += __shfl_xor(s1, msk, 64);
                s2 += __shfl_xor(s2, msk, 64);
                s3 += __shfl_xor(s3, msk, 64);
            }
            if (l16 == 0) {
                int cj = nb * 8 + wn * 4 + j;
                f4 o;
                o[0] = __expf(s0 * -3.125f);
                o[1] = __expf(s1 * -3.125f);
                o[2] = __expf(s2 * -3.125f);
                o[3] = __expf(s3 * -3.125f);
                size_t off = ((size_t)(bidx * 64 + cj)) * HW
                           + (size_t)(hw0 + wm * 64 + i * 16 + qd * 4);
                *(f4*)(out + off) = o;
            }
        }
    }
}

// ---------------------------------------------------------------------------
// Fallback (R2 kernel, LDS-staged B) if ws is too small for W' precompute.
__global__ __launch_bounds__(256) void duq_fallback(
    const float* __restrict__ feat, const float* __restrict__ wts,
    const float* __restrict__ m_in, const float* __restrict__ n_in,
    float* __restrict__ out)
{
    __shared__ __align__(16) unsigned short Ah[128 * 40];
    __shared__ __align__(16) unsigned short Al[128 * 40];
    __shared__ __align__(16) unsigned short Bh[128 * 40];
    __shared__ __align__(16) unsigned short Bl[128 * 40];

    const int t  = threadIdx.x;
    const int bx = blockIdx.x;
    const int nb = bx & 7;
    const int mb = bx >> 3;
    const int bidx = mb >> 7;
    const int hw0  = (mb & 127) << 7;

    const int fb = t & 7;
    const int pb = t >> 3;
    const float* ap = feat + (size_t)bidx * (FDIM * HW) + (size_t)(fb * 4) * HW + (hw0 + pb * 4);

    const int bn  = t >> 1;
    const int bh_ = t & 1;
    const int ng  = nb * 128 + bn;
    const float* bp = wts + (size_t)((ng & 15) * 64 + (ng >> 4)) * FDIM + bh_ * 16;

    unsigned short* awH = &Ah[(pb * 4) * 40 + fb * 4];
    unsigned short* awL = &Al[(pb * 4) * 40 + fb * 4];
    unsigned short* bwH = &Bh[bn * 40 + bh_ * 16];
    unsigned short* bwL = &Bl[bn * 40 + bh_ * 16];

    const int lane = t & 63;
    const int wv = t >> 6;
    const int wm = wv >> 1, wn = wv & 1;
    const int l16 = lane & 15, qd = lane >> 4;

    const unsigned short* arH = &Ah[(wm * 64 + l16) * 40 + qd * 8];
    const unsigned short* arL = &Al[(wm * 64 + l16) * 40 + qd * 8];
    const unsigned short* brH = &Bh[(wn * 64 + l16) * 40 + qd * 8];
    const unsigned short* brL = &Bl[(wn * 64 + l16) * 40 + qd * 8];

    f32x4 acc[4][4] = {};

    f4 av[4], bv[4];
    #pragma unroll
    for (int i = 0; i < 4; ++i) av[i] = *(const f4*)(ap + (size_t)i * HW);
    #pragma unroll
    for (int q = 0; q < 4; ++q) bv[q] = *(const f4*)(bp + q * 4);

    for (int kt = 0; kt < 16; ++kt) {
        __syncthreads();
        #pragma unroll
        for (int j = 0; j < 4; ++j) {
            float a0 = av[0][j], a1 = av[1][j], a2 = av[2][j], a3 = av[3][j];
            u32x2 h, l;
            h[0] = pkhi(a0, a1); h[1] = pkhi(a2, a3);
            l[0] = pklo(a0, a1); l[1] = pklo(a2, a3);
            *(u32x2*)(awH + j * 40) = h;
            *(u32x2*)(awL + j * 40) = l;
        }
        {
            u32x4 h0 = { pkhi(bv[0][0], bv[0][1]), pkhi(bv[0][2], bv[0][3]),
                         pkhi(bv[1][0], bv[1][1]), pkhi(bv[1][2], bv[1][3]) };
            u32x4 h1 = { pkhi(bv[2][0], bv[2][1]), pkhi(bv[2][2], bv[2][3]),
                         pkhi(bv[3][0], bv[3][1]), pkhi(bv[3][2], bv[3][3]) };
            u32x4 l0 = { pklo(bv[0][0], bv[0][1]), pklo(bv[0][2], bv[0][3]),
                         pklo(bv[1][0], bv[1][1]), pklo(bv[1][2], bv[1][3]) };
            u32x4 l1 = { pklo(bv[2][0], bv[2][1]), pklo(bv[2][2], bv[2][3]),
                         pklo(bv[3][0], bv[3][1]), pklo(bv[3][2], bv[3][3]) };
            *(u32x4*)(bwH)     = h0;  *(u32x4*)(bwH + 8) = h1;
            *(u32x4*)(bwL)     = l0;  *(u32x4*)(bwL + 8) = l1;
        }
        __syncthreads();

        if (kt < 15) {
            ap += 32 * HW;
            bp += 32;
            #pragma unroll
            for (int i = 0; i < 4; ++i) av[i] = *(const f4*)(ap + (size_t)i * HW);
            #pragma unroll
            for (int q = 0; q < 4; ++q) bv[q] = *(const f4*)(bp + q * 4);
        }

        bf16x8 fah[4], fal[4];
        #pragma unroll
        for (int i = 0; i < 4; ++i) {
            fah[i] = *(const bf16x8*)(arH + i * 640);
            fal[i] = *(const bf16x8*)(arL + i * 640);
        }
        #pragma unroll
        for (int j = 0; j < 4; ++j) {
            bf16x8 fbh = *(const bf16x8*)(brH + j * 640);
            bf16x8 fbl = *(const bf16x8*)(brL + j * 640);
            #pragma unroll
            for (int i = 0; i < 4; ++i) {
                acc[i][j] = __builtin_amdgcn_mfma_f32_16x16x32_bf16(fah[i], fbh, acc[i][j], 0, 0, 0);
                acc[i][j] = __builtin_amdgcn_mfma_f32_16x16x32_bf16(fah[i], fbl, acc[i][j], 0, 0, 0);
                acc[i][j] = __builtin_amdgcn_mfma_f32_16x16x32_bf16(fal[i], fbh, acc[i][j], 0, 0, 0);
            }
        }
    }

    float centv[4];
    #pragma unroll
    for (int j = 0; j < 4; ++j) {
        int cj = nb * 8 + wn * 4 + j;
        centv[j] = m_in[l16 * 64 + cj] / n_in[cj];
    }
    #pragma unroll
    for (int i = 0; i < 4; ++i) {
        #pragma unroll
        for (int j = 0; j < 4; ++j) {
            float s0 = acc[i][j][0] - centv[j]; s0 *= s0;
            float s1 = acc[i][j][1] - centv[j]; s1 *= s1;
            float s2 = acc[i][j][2] - centv[j]; s2 *= s2;
            float s3 = acc[i][j][3] - centv[j]; s3 *= s3;
            #pragma unroll
            for (int msk = 1; msk < 16; msk <<= 1) {
                s0 += __shfl_xor(s0, msk, 64);
                s1 += __shfl_xor(s1, msk, 64);
                s2 += __shfl_xor(s2, msk, 64);
                s3 += __shfl_xor(s3, msk, 64);
            }
            if (l16 == 0) {
                int cj = nb * 8 + wn * 4 + j;
                f4 o;
                o[0] = __expf(s0 * -3.125f);
                o[1] = __expf(s1 * -3.125f);
                o[2] = __expf(s2 * -3.125f);
                o[3] = __expf(s3 * -3.125f);
                size_t off = ((size_t)(bidx * 64 + cj)) * HW
                           + (size_t)(hw0 + wm * 64 + i * 16 + qd * 4);
                *(f4*)(out + off) = o;
            }
        }
    }
}

extern "C" void kernel_launch(void* const* d_in, const int* in_sizes, int n_in,
                              void* d_out, int out_size, void* d_ws, size_t ws_size,
                              hipStream_t stream) {
    const float* feat = (const float*)d_in[0];
    const float* wts  = (const float*)d_in[1];
    const float* mbuf = (const float*)d_in[2];
    const float* nbuf = (const float*)d_in[3];
    float* out = (float*)d_out;

    // W' needs 2 MB + 128 KB slack (discarded tail prefetch reads past wl end)
    if (ws_size >= (size_t)(2 * 1024 * 1024 + 128 * 1024)) {
        unsigned short* wh = (unsigned short*)d_ws;
        unsigned short* wl = wh + 512 * 1024;   // 1 MB in
        conv_w<<<dim3(256), dim3(256), 0, stream>>>(wts, wh, wl);
        duq_main<<<dim3(1024 * 8), dim3(256), 0, stream>>>(feat, wh, wl, mbuf, nbuf, out);
    } else {
        duq_fallback<<<dim3(1024 * 8), dim3(256), 0, stream>>>(feat, wts, mbuf, nbuf, out);
    }
}

// Round 3
// 691.730 us; speedup vs baseline: 1.6925x; 1.0232x over previous
//
#include <hip/hip_runtime.h>

typedef __attribute__((ext_vector_type(8))) short bf16x8;   // 8 bf16 = 4 VGPRs (MFMA A/B frag)
typedef __attribute__((ext_vector_type(4))) float f32x4;    // MFMA C/D frag
typedef __attribute__((ext_vector_type(4))) float f4;
typedef __attribute__((ext_vector_type(2))) unsigned int u32x2;
typedef __attribute__((ext_vector_type(4))) unsigned int u32x4;

#define HW   16384   // 128*128
#define FDIM 512

// pack bf16(trunc) of a (low 16) and b (high 16) in one v_perm_b32
__device__ __forceinline__ unsigned pkhi(float a, float b) {
    return __builtin_amdgcn_perm(__builtin_bit_cast(unsigned int, b),
                                 __builtin_bit_cast(unsigned int, a),
                                 0x07060302u);
}
__device__ __forceinline__ float trhi(float a) {
    return __builtin_bit_cast(float, __builtin_bit_cast(unsigned int, a) & 0xFFFF0000u);
}
__device__ __forceinline__ unsigned pklo(float a, float b) {
    return pkhi(a - trhi(a), b - trhi(b));
}

// ---------------------------------------------------------------------------
// Prologue: convert W[e,c,f] fp32 -> bf16 hi/lo in d_ws, n-reordered (n=c*16+e)
// and laid out in MFMA B-frag order: W'[kchunk 0..63][n 0..1023][8 bf16].
__global__ __launch_bounds__(256) void conv_w(const float* __restrict__ wts,
                                              unsigned short* __restrict__ wh,
                                              unsigned short* __restrict__ wl) {
    const int tid = blockIdx.x * 256 + threadIdx.x;   // 65536 threads
    const int n  = tid & 1023;
    const int kc = tid >> 10;                         // k-chunk 0..63
    const float* src = wts + (size_t)((n & 15) * 64 + (n >> 4)) * FDIM + kc * 8;
    f4 a = *(const f4*)src, b = *(const f4*)(src + 4);
    u32x4 h = { pkhi(a[0], a[1]), pkhi(a[2], a[3]), pkhi(b[0], b[1]), pkhi(b[2], b[3]) };
    u32x4 l = { pklo(a[0], a[1]), pklo(a[2], a[3]), pklo(b[0], b[1]), pklo(b[2], b[3]) };
    size_t off = ((size_t)kc * 1024 + n) * 8;
    *(u32x4*)(wh + off) = h;    // 16 B per thread, consecutive n -> coalesced
    *(u32x4*)(wl + off) = l;
}

// ---------------------------------------------------------------------------
// Main (R3): NO LDS, NO barriers. R2 evidence: HBM at 5.7% peak, MfmaUtil 37%,
// ~30% of cycles neither-pipe-issuing = barrier/LDS-transpose stall. Each lane
// loads its A-frag elements (8 k-strided fp32 for its fixed pixel) DIRECTLY
// from global (16 lanes x consecutive pixels = 64 B segments, L2-hot via XCD
// swizzle) and packs hi/lo bf16 in-register. A is ping-pong double-buffered
// across K-steps so next-kt loads fly under current-kt MFMAs. Numerically
// identical to R2 (same split, same MFMA sequence).
__global__ __launch_bounds__(256, 2) void duq_direct(
    const float* __restrict__ feat,          // [8,512,128,128]
    const unsigned short* __restrict__ wh,   // [64][1024][8] bf16 hi
    const unsigned short* __restrict__ wl,   // [64][1024][8] bf16 lo
    const float* __restrict__ m_in,          // [16,64]
    const float* __restrict__ n_in,          // [64]
    float* __restrict__ out)                 // [8,64,128,128]
{
    const int t  = threadIdx.x;
    const int bx = blockIdx.x;
    // XCD swizzle (proven R2: FETCH 1.07 GB -> 0.17 GB): (bx&7) = XCD id;
    // each XCD owns a contiguous mb range, 8 nb-siblings dispatch-adjacent.
    const int kb = bx >> 3;
    const int nb = kb & 7;                    // N block: 1024/128
    const int mb = (bx & 7) * 128 + (kb >> 3);
    const int bidx = mb >> 7;
    const int hw0  = (mb & 127) << 7;

    const int lane = t & 63;
    const int wv = t >> 6;
    const int wm = wv >> 1, wn = wv & 1;      // 2x2 waves, 64x64 each
    const int l16 = lane & 15, qd = lane >> 4;

    // A: lane (l16,qd) of wave wm owns pixel p = hw0 + wm*64 + l16 + i*16 and
    // k-chunk qd*8 within each 32-k tile. Moving ptr advanced 32*HW per ldA.
    const float* apc = feat + (size_t)bidx * (FDIM * HW)
                     + (size_t)(qd * 8) * HW + (hw0 + wm * 64 + l16);

    // B frag base for this lane: frag (kt,j) is 16 B at bgh + kt*32768 + j*128
    const size_t bgoff = ((size_t)qd * 1024 + (size_t)(nb * 128 + wn * 64 + l16)) * 8;
    const unsigned short* bgh = wh + bgoff;
    const unsigned short* bgl = wl + bgoff;

    f32x4 acc[4][4] = {};

    // preload B-frag (kt=0, j=0)
    bf16x8 cbh = *(const bf16x8*)(bgh);
    bf16x8 cbl = *(const bf16x8*)(bgl);
    size_t boff = 0;

    // issue one kt's 32 A loads (4 i x 8 j); i*16 pixels = 64 B -> imm offsets
    auto ldA = [&](float (&dst)[4][8]) {
        #pragma unroll
        for (int j = 0; j < 8; ++j) {
            const float* r = apc + (size_t)j * HW;
            #pragma unroll
            for (int i = 0; i < 4; ++i) dst[i][j] = r[i * 16];
        }
        apc += 32 * HW;
    };

    // pack one kt's A to bf16 hi/lo frags and run the 48-MFMA j-loop with
    // j-pipelined B prefetch from L2
    auto step = [&](float (&av)[4][8]) {
        bf16x8 fah[4], fal[4];
        #pragma unroll
        for (int i = 0; i < 4; ++i) {
            u32x4 hh = { pkhi(av[i][0], av[i][1]), pkhi(av[i][2], av[i][3]),
                         pkhi(av[i][4], av[i][5]), pkhi(av[i][6], av[i][7]) };
            u32x4 ll = { pklo(av[i][0], av[i][1]), pklo(av[i][2], av[i][3]),
                         pklo(av[i][4], av[i][5]), pklo(av[i][6], av[i][7]) };
            fah[i] = __builtin_bit_cast(bf16x8, hh);
            fal[i] = __builtin_bit_cast(bf16x8, ll);
        }
        #pragma unroll
        for (int j = 0; j < 4; ++j) {
            size_t bnext = boff + ((j == 3) ? (size_t)(32768 - 384) : (size_t)128);
            bf16x8 nbh = *(const bf16x8*)(bgh + bnext);   // final (kt=15,j=3) load is
            bf16x8 nbl = *(const bf16x8*)(bgl + bnext);   // discarded (ws slack covers OOB)
            #pragma unroll
            for (int i = 0; i < 4; ++i) {
                acc[i][j] = __builtin_amdgcn_mfma_f32_16x16x32_bf16(fah[i], cbh, acc[i][j], 0, 0, 0);
                acc[i][j] = __builtin_amdgcn_mfma_f32_16x16x32_bf16(fah[i], cbl, acc[i][j], 0, 0, 0);
                acc[i][j] = __builtin_amdgcn_mfma_f32_16x16x32_bf16(fal[i], cbh, acc[i][j], 0, 0, 0);
            }
            cbh = nbh; cbl = nbl; boff = bnext;
        }
    };

    // ping-pong A across kt: named buffers, static indexing only (no dynamic
    // index -> no scratch). ldA call order is kt = 0,1,2,...,15.
    float avA[4][8], avB[4][8];
    ldA(avA);                         // kt 0
    #pragma unroll 1
    for (int kt2 = 0; kt2 < 8; ++kt2) {
        ldA(avB);                     // kt 2*kt2+1
        step(avA);                    // compute kt 2*kt2
        if (kt2 < 7) ldA(avA);        // kt 2*kt2+2
        step(avB);                    // compute kt 2*kt2+1
    }

    // ---- epilogue: subtract centroid, square, e-reduce (16 lanes), exp, store
    float centv[4];
    #pragma unroll
    for (int j = 0; j < 4; ++j) {
        int cj = nb * 8 + wn * 4 + j;
        centv[j] = m_in[l16 * 64 + cj] / n_in[cj];
    }
    #pragma unroll
    for (int i = 0; i < 4; ++i) {
        #pragma unroll
        for (int j = 0; j < 4; ++j) {
            float s0 = acc[i][j][0] - centv[j]; s0 *= s0;
            float s1 = acc[i][j][1] - centv[j]; s1 *= s1;
            float s2 = acc[i][j][2] - centv[j]; s2 *= s2;
            float s3 = acc[i][j][3] - centv[j]; s3 *= s3;
            #pragma unroll
            for (int msk = 1; msk < 16; msk <<= 1) {
                s0 += __shfl_xor(s0, msk, 64);
                s1 += __shfl_xor(s1, msk, 64);
                s2 += __shfl_xor(s2, msk, 64);
                s3 += __shfl_xor(s3, msk, 64);
            }
            if (l16 == 0) {
                int cj = nb * 8 + wn * 4 + j;
                f4 o;
                o[0] = __expf(s0 * -3.125f);
                o[1] = __expf(s1 * -3.125f);
                o[2] = __expf(s2 * -3.125f);
                o[3] = __expf(s3 * -3.125f);
                size_t off = ((size_t)(bidx * 64 + cj)) * HW
                           + (size_t)(hw0 + wm * 64 + i * 16 + qd * 4);
                *(f4*)(out + off) = o;
            }
        }
    }
}

// ---------------------------------------------------------------------------
// Fallback (LDS-staged A and B) if ws is too small for W' precompute.
__global__ __launch_bounds__(256) void duq_fallback(
    const float* __restrict__ feat, const float* __restrict__ wts,
    const float* __restrict__ m_in, const float* __restrict__ n_in,
    float* __restrict__ out)
{
    __shared__ __align__(16) unsigned short Ah[128 * 40];
    __shared__ __align__(16) unsigned short Al[128 * 40];
    __shared__ __align__(16) unsigned short Bh[128 * 40];
    __shared__ __align__(16) unsigned short Bl[128 * 40];

    const int t  = threadIdx.x;
    const int bx = blockIdx.x;
    const int nb = bx & 7;
    const int mb = bx >> 3;
    const int bidx = mb >> 7;
    const int hw0  = (mb & 127) << 7;

    const int fb = t & 7;
    const int pb = t >> 3;
    const float* ap = feat + (size_t)bidx * (FDIM * HW) + (size_t)(fb * 4) * HW + (hw0 + pb * 4);

    const int bn  = t >> 1;
    const int bh_ = t & 1;
    const int ng  = nb * 128 + bn;
    const float* bp = wts + (size_t)((ng & 15) * 64 + (ng >> 4)) * FDIM + bh_ * 16;

    unsigned short* awH = &Ah[(pb * 4) * 40 + fb * 4];
    unsigned short* awL = &Al[(pb * 4) * 40 + fb * 4];
    unsigned short* bwH = &Bh[bn * 40 + bh_ * 16];
    unsigned short* bwL = &Bl[bn * 40 + bh_ * 16];

    const int lane = t & 63;
    const int wv = t >> 6;
    const int wm = wv >> 1, wn = wv & 1;
    const int l16 = lane & 15, qd = lane >> 4;

    const unsigned short* arH = &Ah[(wm * 64 + l16) * 40 + qd * 8];
    const unsigned short* arL = &Al[(wm * 64 + l16) * 40 + qd * 8];
    const unsigned short* brH = &Bh[(wn * 64 + l16) * 40 + qd * 8];
    const unsigned short* brL = &Bl[(wn * 64 + l16) * 40 + qd * 8];

    f32x4 acc[4][4] = {};

    f4 av[4], bv[4];
    #pragma unroll
    for (int i = 0; i < 4; ++i) av[i] = *(const f4*)(ap + (size_t)i * HW);
    #pragma unroll
    for (int q = 0; q < 4; ++q) bv[q] = *(const f4*)(bp + q * 4);

    for (int kt = 0; kt < 16; ++kt) {
        __syncthreads();
        #pragma unroll
        for (int j = 0; j < 4; ++j) {
            float a0 = av[0][j], a1 = av[1][j], a2 = av[2][j], a3 = av[3][j];
            u32x2 h, l;
            h[0] = pkhi(a0, a1); h[1] = pkhi(a2, a3);
            l[0] = pklo(a0, a1); l[1] = pklo(a2, a3);
            *(u32x2*)(awH + j * 40) = h;
            *(u32x2*)(awL + j * 40) = l;
        }
        {
            u32x4 h0 = { pkhi(bv[0][0], bv[0][1]), pkhi(bv[0][2], bv[0][3]),
                         pkhi(bv[1][0], bv[1][1]), pkhi(bv[1][2], bv[1][3]) };
            u32x4 h1 = { pkhi(bv[2][0], bv[2][1]), pkhi(bv[2][2], bv[2][3]),
                         pkhi(bv[3][0], bv[3][1]), pkhi(bv[3][2], bv[3][3]) };
            u32x4 l0 = { pklo(bv[0][0], bv[0][1]), pklo(bv[0][2], bv[0][3]),
                         pklo(bv[1][0], bv[1][1]), pklo(bv[1][2], bv[1][3]) };
            u32x4 l1 = { pklo(bv[2][0], bv[2][1]), pklo(bv[2][2], bv[2][3]),
                         pklo(bv[3][0], bv[3][1]), pklo(bv[3][2], bv[3][3]) };
            *(u32x4*)(bwH)     = h0;  *(u32x4*)(bwH + 8) = h1;
            *(u32x4*)(bwL)     = l0;  *(u32x4*)(bwL + 8) = l1;
        }
        __syncthreads();

        if (kt < 15) {
            ap += 32 * HW;
            bp += 32;
            #pragma unroll
            for (int i = 0; i < 4; ++i) av[i] = *(const f4*)(ap + (size_t)i * HW);
            #pragma unroll
            for (int q = 0; q < 4; ++q) bv[q] = *(const f4*)(bp + q * 4);
        }

        bf16x8 fah[4], fal[4];
        #pragma unroll
        for (int i = 0; i < 4; ++i) {
            fah[i] = *(const bf16x8*)(arH + i * 640);
            fal[i] = *(const bf16x8*)(arL + i * 640);
        }
        #pragma unroll
        for (int j = 0; j < 4; ++j) {
            bf16x8 fbh = *(const bf16x8*)(brH + j * 640);
            bf16x8 fbl = *(const bf16x8*)(brL + j * 640);
            #pragma unroll
            for (int i = 0; i < 4; ++i) {
                acc[i][j] = __builtin_amdgcn_mfma_f32_16x16x32_bf16(fah[i], fbh, acc[i][j], 0, 0, 0);
                acc[i][j] = __builtin_amdgcn_mfma_f32_16x16x32_bf16(fah[i], fbl, acc[i][j], 0, 0, 0);
                acc[i][j] = __builtin_amdgcn_mfma_f32_16x16x32_bf16(fal[i], fbh, acc[i][j], 0, 0, 0);
            }
        }
    }

    float centv[4];
    #pragma unroll
    for (int j = 0; j < 4; ++j) {
        int cj = nb * 8 + wn * 4 + j;
        centv[j] = m_in[l16 * 64 + cj] / n_in[cj];
    }
    #pragma unroll
    for (int i = 0; i < 4; ++i) {
        #pragma unroll
        for (int j = 0; j < 4; ++j) {
            float s0 = acc[i][j][0] - centv[j]; s0 *= s0;
            float s1 = acc[i][j][1] - centv[j]; s1 *= s1;
            float s2 = acc[i][j][2] - centv[j]; s2 *= s2;
            float s3 = acc[i][j][3] - centv[j]; s3 *= s3;
            #pragma unroll
            for (int msk = 1; msk < 16; msk <<= 1) {
                s0 += __shfl_xor(s0, msk, 64);
                s1 += __shfl_xor(s1, msk, 64);
                s2 += __shfl_xor(s2, msk, 64);
                s3 += __shfl_xor(s3, msk, 64);
            }
            if (l16 == 0) {
                int cj = nb * 8 + wn * 4 + j;
                f4 o;
                o[0] = __expf(s0 * -3.125f);
                o[1] = __expf(s1 * -3.125f);
                o[2] = __expf(s2 * -3.125f);
                o[3] = __expf(s3 * -3.125f);
                size_t off = ((size_t)(bidx * 64 + cj)) * HW
                           + (size_t)(hw0 + wm * 64 + i * 16 + qd * 4);
                *(f4*)(out + off) = o;
            }
        }
    }
}

extern "C" void kernel_launch(void* const* d_in, const int* in_sizes, int n_in,
                              void* d_out, int out_size, void* d_ws, size_t ws_size,
                              hipStream_t stream) {
    const float* feat = (const float*)d_in[0];
    const float* wts  = (const float*)d_in[1];
    const float* mbuf = (const float*)d_in[2];
    const float* nbuf = (const float*)d_in[3];
    float* out = (float*)d_out;

    // W' needs 2 MB + 128 KB slack (discarded tail prefetch reads past wl end)
    if (ws_size >= (size_t)(2 * 1024 * 1024 + 128 * 1024)) {
        unsigned short* wh = (unsigned short*)d_ws;
        unsigned short* wl = wh + 512 * 1024;   // 1 MB in
        conv_w<<<dim3(256), dim3(256), 0, stream>>>(wts, wh, wl);
        duq_direct<<<dim3(1024 * 8), dim3(256), 0, stream>>>(feat, wh, wl, mbuf, nbuf, out);
    } else {
        duq_fallback<<<dim3(1024 * 8), dim3(256), 0, stream>>>(feat, wts, mbuf, nbuf, out);
    }
}